// Round 3
// baseline (146.452 us; speedup 1.0000x reference)
//
#include <hip/hip_runtime.h>

#define B 32
#define T 65536
#define EPSF 1e-7f
#define TPB 256
#define CHUNK 2048               // 8 t per thread
#define NCHUNKB (T / CHUNK)      // 32 chunks per b
#define NBLK (B * NCHUNKB)       // 1024 blocks
#define NACC 21                  // 16 term1 + 4 term2 + 1 vad
#define NCOL (B * NACC)          // 672
// ws layout: sums[NCOL] floats + counter int = 2692 B, memset to 0 per launch

__device__ __forceinline__ float wave_reduce_sum(float v) {
    #pragma unroll
    for (int off = 32; off > 0; off >>= 1) v += __shfl_down(v, off, 64);
    return v;
}

__device__ __forceinline__ void accum_sp(float4 p4, float4 l4,
                                         float (&a1)[16], float (&a2)[4]) {
    const float p[4] = {p4.x, p4.y, p4.z, p4.w};
    const float l[4] = {l4.x, l4.y, l4.z, l4.w};
    float d[4];
    #pragma unroll
    for (int i = 0; i < 4; ++i) {
        const float pc = fminf(fmaxf(p[i], EPSF), 1.0f - EPSF);
        const float lp = __logf(pc);
        const float lq = __logf(1.0f - pc);
        a2[i] += lq;
        d[i] = lp - lq;
    }
    #pragma unroll
    for (int i = 0; i < 4; ++i)
        #pragma unroll
        for (int j = 0; j < 4; ++j)
            a1[i * 4 + j] = fmaf(d[i], l[j], a1[i * 4 + j]);
}

__device__ __forceinline__ void accum_vad1(float pvv, float vdd, float& av) {
    const float pvc = fminf(fmaxf(pvv, EPSF), 1.0f - EPSF);
    av += __logf((vdd > 0.5f) ? pvc : (1.0f - pvc));  // vad is exactly 0/1
}

__device__ __forceinline__ void accum_vad4(float4 v4, float4 w4, float& av) {
    accum_vad1(v4.x, w4.x, av);
    accum_vad1(v4.y, w4.y, av);
    accum_vad1(v4.z, w4.z, av);
    accum_vad1(v4.w, w4.w, av);
}

__global__ __launch_bounds__(TPB) void fused_kernel(
    const float4* __restrict__ ps,   // pred_speakers [B,T,4]
    const float*  __restrict__ pv,   // pred_vad [B,T]
    const float4* __restrict__ lb,   // labels [B,T,4]
    const float*  __restrict__ vd,   // vad [B,T]
    const int*    __restrict__ len,  // lengths [B] int32
    float* __restrict__ sums_g,      // [NCOL] zeroed accumulators
    int*   __restrict__ counter,     // zeroed block-done counter
    float* __restrict__ out)
{
    const int b  = blockIdx.x >> 5;          // / NCHUNKB
    const int c  = blockIdx.x & (NCHUNKB - 1);
    const int t0 = c * CHUNK;
    const int L  = len[b];
    const int tid = threadIdx.x;

    float a1[16], a2[4], av = 0.0f;
    #pragma unroll
    for (int k = 0; k < 16; ++k) a1[k] = 0.0f;
    #pragma unroll
    for (int k = 0; k < 4; ++k)  a2[k] = 0.0f;

    if (t0 < L) {                            // block-uniform prefix mask
        if (t0 + CHUNK <= L) {
            // fast path, two 4-t hoisted batches (keeps VGPR < 128)
            const int base = b * T + t0 + tid;

            float4 P0[4], Q0[4];
            #pragma unroll
            for (int u = 0; u < 4; ++u) {
                const int g = base + u * TPB;
                P0[u] = ps[g];  Q0[u] = lb[g];
            }
            // VAD: this thread owns 8 CONSECUTIVE t -> pure float4 traffic
            const int gv = b * T + t0 + tid * 8;
            const float4 V0 = *reinterpret_cast<const float4*>(pv + gv);
            const float4 V1 = *reinterpret_cast<const float4*>(pv + gv + 4);
            const float4 W0 = *reinterpret_cast<const float4*>(vd + gv);
            const float4 W1 = *reinterpret_cast<const float4*>(vd + gv + 4);

            #pragma unroll
            for (int u = 0; u < 4; ++u)
                accum_sp(P0[u], Q0[u], a1, a2);

            float4 P1[4], Q1[4];
            #pragma unroll
            for (int u = 0; u < 4; ++u) {
                const int g = base + (4 + u) * TPB;
                P1[u] = ps[g];  Q1[u] = lb[g];
            }
            #pragma unroll
            for (int u = 0; u < 4; ++u)
                accum_sp(P1[u], Q1[u], a1, a2);

            accum_vad4(V0, W0, av);
            accum_vad4(V1, W1, av);
        } else {
            // boundary chunk (at most one per b): per-lane predicate
            #pragma unroll
            for (int u = 0; u < 8; ++u) {
                const int t = t0 + tid + u * TPB;
                if (t < L) {
                    const int g = b * T + t;
                    const float4 p4 = ps[g];
                    const float4 l4 = lb[g];
                    accum_sp(p4, l4, a1, a2);
                    accum_vad1(pv[g], vd[g], av);
                }
            }
        }
    }

    // ---- block-reduce 21 partials ----
    __shared__ float smem[TPB / 64][NACC];
    __shared__ int s_last;
    const int lane = tid & 63;
    const int wv   = tid >> 6;

    float vals[NACC];
    #pragma unroll
    for (int k = 0; k < 16; ++k) vals[k] = a1[k];
    #pragma unroll
    for (int k = 0; k < 4; ++k)  vals[16 + k] = a2[k];
    vals[20] = av;

    #pragma unroll
    for (int k = 0; k < NACC; ++k) {
        const float r = wave_reduce_sum(vals[k]);
        if (lane == 0) smem[wv][k] = r;
    }
    __syncthreads();

    // ---- device-scope accumulate (fp32 HW atomics, coherent point) ----
    if (tid < NACC) {
        float s = 0.0f;
        #pragma unroll
        for (int w = 0; w < TPB / 64; ++w) s += smem[w][tid];
        atomicAdd(&sums_g[b * NACC + tid], s);
    }
    // compiler emits s_waitcnt vmcnt(0) before s_barrier -> RMWs complete
    __syncthreads();
    if (tid == 0) {
        const int old = __hip_atomic_fetch_add(counter, 1, __ATOMIC_ACQ_REL,
                                               __HIP_MEMORY_SCOPE_AGENT);
        s_last = (old == NBLK - 1) ? 1 : 0;
    }
    __syncthreads();
    if (!s_last) return;

    // ---- last-finished block computes the final scalar ----
    __threadfence();   // acquire side
    __shared__ float sums[B][NACC];
    for (int col = tid; col < NCOL; col += TPB) {
        // agent-scope load: bypass possibly-stale per-XCD L2 (G16)
        const float v = __hip_atomic_load(&sums_g[col], __ATOMIC_RELAXED,
                                          __HIP_MEMORY_SCOPE_AGENT);
        sums[col / NACC][col % NACC] = v;
    }
    __syncthreads();

    if (tid < 64) {
        float best = 0.0f, vadn = 0.0f, lensum = 0.0f;
        if (tid < B) {
            const int bb = tid;
            const float msum = (float)len[bb];
            float Lm[16];
            #pragma unroll
            for (int i = 0; i < 4; ++i)
                #pragma unroll
                for (int j = 0; j < 4; ++j)
                    Lm[i * 4 + j] = (-sums[bb][i * 4 + j] - sums[bb][16 + i]) / msum;

            best = 1e30f;
            #pragma unroll
            for (int p0 = 0; p0 < 4; ++p0)
                #pragma unroll
                for (int p1 = 0; p1 < 4; ++p1) {
                    if (p1 == p0) continue;
                    #pragma unroll
                    for (int p2 = 0; p2 < 4; ++p2) {
                        if (p2 == p0 || p2 == p1) continue;
                        const int p3 = 6 - p0 - p1 - p2;
                        best = fminf(best, Lm[p0] + Lm[4 + p1] + Lm[8 + p2] + Lm[12 + p3]);
                    }
                }
            best *= 0.25f;                 // mean over S
            vadn   = -sums[bb][20];        // masked VAD BCE numerator
            lensum = msum;
        }
        best   = wave_reduce_sum(best);
        vadn   = wave_reduce_sum(vadn);
        lensum = wave_reduce_sum(lensum);
        if (tid == 0)
            out[0] = best * (1.0f / B) + 0.5f * (vadn / lensum);
    }
}

extern "C" void kernel_launch(void* const* d_in, const int* in_sizes, int n_in,
                              void* d_out, int out_size, void* d_ws, size_t ws_size,
                              hipStream_t stream) {
    const float4* ps  = (const float4*)d_in[0];
    const float*  pv  = (const float*)d_in[1];
    const float4* lb  = (const float4*)d_in[2];
    const float*  vd  = (const float*)d_in[3];
    const int*    len = (const int*)d_in[4];
    float*        sums_g  = (float*)d_ws;            // NCOL floats
    int*          counter = (int*)((float*)d_ws + NCOL);
    float*        out  = (float*)d_out;

    // zero the 672 accumulators + counter (graph-capturable async memset)
    hipMemsetAsync(d_ws, 0, (NCOL + 1) * sizeof(float), stream);

    void* kp0 = (void*)ps;  // silence unused warnings pattern not needed; direct launch:
    (void)kp0;
    fused_kernel<<<NBLK, TPB, 0, stream>>>(ps, pv, lb, vd, len, sums_g, counter, out);
}

// Round 4
// 113.411 us; speedup vs baseline: 1.2913x; 1.2913x over previous
//
#include <hip/hip_runtime.h>

#define B 32
#define T 65536
#define EPSF 1e-7f
#define TPB 256
#define CHUNK 2048               // 8 t per thread
#define NCHUNKB (T / CHUNK)      // 32 chunks per b
#define NBLK (B * NCHUNKB)       // 1024 blocks
#define NACC 21                  // 16 term1 + 4 term2 + 1 vad
#define NCOL (B * NACC)          // 672
// ws layout: part[NCHUNKB][B*NACC] floats = 32*672 = 21504 floats (86 KB)

__device__ __forceinline__ float wave_reduce_sum(float v) {
    #pragma unroll
    for (int off = 32; off > 0; off >>= 1) v += __shfl_down(v, off, 64);
    return v;
}

__device__ __forceinline__ void accum_sp(float4 p4, float4 l4,
                                         float (&a1)[16], float (&a2)[4]) {
    const float p[4] = {p4.x, p4.y, p4.z, p4.w};
    const float l[4] = {l4.x, l4.y, l4.z, l4.w};
    float d[4];
    #pragma unroll
    for (int i = 0; i < 4; ++i) {
        const float pc = fminf(fmaxf(p[i], EPSF), 1.0f - EPSF);
        const float lp = __logf(pc);
        const float lq = __logf(1.0f - pc);
        a2[i] += lq;
        d[i] = lp - lq;
    }
    #pragma unroll
    for (int i = 0; i < 4; ++i)
        #pragma unroll
        for (int j = 0; j < 4; ++j)
            a1[i * 4 + j] = fmaf(d[i], l[j], a1[i * 4 + j]);
}

__device__ __forceinline__ void accum_vad1(float pvv, float vdd, float& av) {
    const float pvc = fminf(fmaxf(pvv, EPSF), 1.0f - EPSF);
    av += __logf((vdd > 0.5f) ? pvc : (1.0f - pvc));  // vad is exactly 0/1
}

__device__ __forceinline__ void accum_vad4(float4 v4, float4 w4, float& av) {
    accum_vad1(v4.x, w4.x, av);
    accum_vad1(v4.y, w4.y, av);
    accum_vad1(v4.z, w4.z, av);
    accum_vad1(v4.w, w4.w, av);
}

// waves_per_eu(4,4): pin occupancy target to 4 waves/SIMD (16 waves/CU,
// 4 blocks/CU, VGPR budget 128). R3 showed the backend's occupancy
// heuristic can squeeze this kernel to 40 VGPR, de-hoisting the float4
// load batches and destroying memory-level parallelism (60 us vs ~20 us).
__global__ __launch_bounds__(TPB)
__attribute__((amdgpu_waves_per_eu(4, 4)))
void partial_kernel(
    const float4* __restrict__ ps,   // pred_speakers [B,T,4]
    const float*  __restrict__ pv,   // pred_vad [B,T]
    const float4* __restrict__ lb,   // labels [B,T,4]
    const float*  __restrict__ vd,   // vad [B,T]
    const int*    __restrict__ len,  // lengths [B] int32
    float* __restrict__ part)        // [NCHUNKB][B*NACC]
{
    const int b  = blockIdx.x >> 5;          // / NCHUNKB
    const int c  = blockIdx.x & (NCHUNKB - 1);
    const int t0 = c * CHUNK;
    const int L  = len[b];
    const int tid = threadIdx.x;

    float a1[16], a2[4], av = 0.0f;
    #pragma unroll
    for (int k = 0; k < 16; ++k) a1[k] = 0.0f;
    #pragma unroll
    for (int k = 0; k < 4; ++k)  a2[k] = 0.0f;

    if (t0 < L) {                            // block-uniform prefix mask
        if (t0 + CHUNK <= L) {
            // fast path, two 4-t hoisted batches (fits 128-VGPR budget)
            const int base = b * T + t0 + tid;

            // batch 0 speaker loads + all VAD loads issued together
            float4 P0[4], Q0[4];
            #pragma unroll
            for (int u = 0; u < 4; ++u) {
                const int g = base + u * TPB;
                P0[u] = ps[g];  Q0[u] = lb[g];
            }
            // VAD: this thread owns 8 CONSECUTIVE t -> pure float4 traffic
            const int gv = b * T + t0 + tid * 8;
            const float4 V0 = *reinterpret_cast<const float4*>(pv + gv);
            const float4 V1 = *reinterpret_cast<const float4*>(pv + gv + 4);
            const float4 W0 = *reinterpret_cast<const float4*>(vd + gv);
            const float4 W1 = *reinterpret_cast<const float4*>(vd + gv + 4);

            #pragma unroll
            for (int u = 0; u < 4; ++u)
                accum_sp(P0[u], Q0[u], a1, a2);

            // batch 1 speaker loads
            float4 P1[4], Q1[4];
            #pragma unroll
            for (int u = 0; u < 4; ++u) {
                const int g = base + (4 + u) * TPB;
                P1[u] = ps[g];  Q1[u] = lb[g];
            }
            #pragma unroll
            for (int u = 0; u < 4; ++u)
                accum_sp(P1[u], Q1[u], a1, a2);

            accum_vad4(V0, W0, av);
            accum_vad4(V1, W1, av);
        } else {
            // boundary chunk (at most one per b): scalar per-lane predicate
            #pragma unroll
            for (int u = 0; u < 8; ++u) {
                const int t = t0 + tid + u * TPB;
                if (t < L) {
                    const int g = b * T + t;
                    const float4 p4 = ps[g];
                    const float4 l4 = lb[g];
                    accum_sp(p4, l4, a1, a2);
                    accum_vad1(pv[g], vd[g], av);
                }
            }
        }
    }

    // block-reduce 21 partials, then one plain store per cell (no init, no atomics)
    __shared__ float smem[TPB / 64][NACC];
    const int lane = tid & 63;
    const int wv   = tid >> 6;

    float vals[NACC];
    #pragma unroll
    for (int k = 0; k < 16; ++k) vals[k] = a1[k];
    #pragma unroll
    for (int k = 0; k < 4; ++k)  vals[16 + k] = a2[k];
    vals[20] = av;

    #pragma unroll
    for (int k = 0; k < NACC; ++k) {
        const float r = wave_reduce_sum(vals[k]);
        if (lane == 0) smem[wv][k] = r;
    }
    __syncthreads();
    if (tid < NACC) {
        float s = 0.0f;
        #pragma unroll
        for (int w = 0; w < TPB / 64; ++w) s += smem[w][tid];
        part[c * NCOL + b * NACC + tid] = s;   // unconditional write
    }
}

__global__ __launch_bounds__(704) void final_kernel(
    const float* __restrict__ part,   // [NCHUNKB][B*NACC]
    const int*   __restrict__ len,
    float* __restrict__ out)
{
    __shared__ float sums[B][NACC];
    const int tid = threadIdx.x;

    if (tid < NCOL) {
        // coalesced: consecutive tid -> consecutive addresses; 32 strided rows
        float a = 0.0f;
        #pragma unroll
        for (int c = 0; c < NCHUNKB; ++c)
            a += part[c * NCOL + tid];
        sums[tid / NACC][tid % NACC] = a;
    }
    __syncthreads();

    if (tid < 64) {
        float best = 0.0f, vadn = 0.0f, lensum = 0.0f;
        if (tid < B) {
            const int bb = tid;
            const float msum = (float)len[bb];
            float Lm[16];
            #pragma unroll
            for (int i = 0; i < 4; ++i)
                #pragma unroll
                for (int j = 0; j < 4; ++j)
                    Lm[i * 4 + j] = (-sums[bb][i * 4 + j] - sums[bb][16 + i]) / msum;

            best = 1e30f;
            #pragma unroll
            for (int p0 = 0; p0 < 4; ++p0)
                #pragma unroll
                for (int p1 = 0; p1 < 4; ++p1) {
                    if (p1 == p0) continue;
                    #pragma unroll
                    for (int p2 = 0; p2 < 4; ++p2) {
                        if (p2 == p0 || p2 == p1) continue;
                        const int p3 = 6 - p0 - p1 - p2;
                        best = fminf(best, Lm[p0] + Lm[4 + p1] + Lm[8 + p2] + Lm[12 + p3]);
                    }
                }
            best *= 0.25f;                 // mean over S
            vadn   = -sums[bb][20];        // masked VAD BCE numerator
            lensum = msum;
        }
        best   = wave_reduce_sum(best);
        vadn   = wave_reduce_sum(vadn);
        lensum = wave_reduce_sum(lensum);
        if (tid == 0)
            out[0] = best * (1.0f / B) + 0.5f * (vadn / lensum);
    }
}

extern "C" void kernel_launch(void* const* d_in, const int* in_sizes, int n_in,
                              void* d_out, int out_size, void* d_ws, size_t ws_size,
                              hipStream_t stream) {
    const float4* ps  = (const float4*)d_in[0];
    const float*  pv  = (const float*)d_in[1];
    const float4* lb  = (const float4*)d_in[2];
    const float*  vd  = (const float*)d_in[3];
    const int*    len = (const int*)d_in[4];
    float*        part = (float*)d_ws;     // NCHUNKB*B*NACC floats
    float*        out  = (float*)d_out;

    partial_kernel<<<NBLK, TPB, 0, stream>>>(ps, pv, lb, vd, len, part);
    final_kernel<<<1, 704, 0, stream>>>(part, len, out);
}